// Round 10
// baseline (317.042 us; speedup 1.0000x reference)
//
#include <hip/hip_runtime.h>

#define HH 51
#define TT 256
#define NB 16
#define L2E 1.442695041f

typedef __attribute__((ext_vector_type(8))) _Float16 half8;
typedef __attribute__((ext_vector_type(4))) float   floatx4;
typedef __attribute__((ext_vector_type(2))) float   float2v;

#define MFMA16F(A,B,C) __builtin_amdgcn_mfma_f32_16x16x32_f16((A),(B),(C),0,0,0)

__device__ __forceinline__ float rcp_fast(float x) { return __builtin_amdgcn_rcpf(x); }
#if __has_builtin(__builtin_amdgcn_exp2f)
__device__ __forceinline__ float exp2_fast(float x) { return __builtin_amdgcn_exp2f(x); }
#else
__device__ __forceinline__ float exp2_fast(float x) { return __expf(0.69314718056f * x); }
#endif
__device__ __forceinline__ unsigned short f2h_bits(float v) {
    return __builtin_bit_cast(unsigned short, (_Float16)v);
}
#if __has_builtin(__builtin_elementwise_fma)
__device__ __forceinline__ float2v fma2(float2v a, float2v b, float2v c) {
    return __builtin_elementwise_fma(a, b, c);
}
#else
__device__ __forceinline__ float2v fma2(float2v a, float2v b, float2v c) {
    float2v r; r.x = fmaf(a.x, b.x, c.x); r.y = fmaf(a.y, b.y, c.y); return r;
}
#endif

// barrier that drains ONLY lgkmcnt (R9; ~neutral but kept as best base)
__device__ __forceinline__ void bar_lgkm() {
    asm volatile("s_waitcnt lgkmcnt(0)" ::: "memory");
    __builtin_amdgcn_s_barrier();
    asm volatile("" ::: "memory");
}

// ------------- weight pre-pack: fp16 hi/lo fragments, K-column folding ---
// (UNCHANGED. Main kernel loads ONLY the hi fragments (hl=0).)
__global__ void lstm_prep(const float* __restrict__ Whh1, const float* __restrict__ Wih1,
                          const float* __restrict__ bih1, const float* __restrict__ bhh1,
                          const float* __restrict__ Wih2, const float* __restrict__ Whh2,
                          const float* __restrict__ bih2, const float* __restrict__ bhh2,
                          const float* __restrict__ Wlin, const float* __restrict__ blin,
                          uint4* __restrict__ frags) {
    int tid = blockIdx.x * blockDim.x + threadIdx.x;
    if (tid >= 196 * 64) return;
    int f = tid >> 6, lane = tid & 63;
    int n = lane & 15, qq = lane >> 4;
    int hl, s, tau, cell;
    if (f < 64)       { cell = 1; int r = f;       hl = r & 1; r >>= 1; s = r & 1; tau = r >> 1; }
    else if (f < 192) { cell = 2; int r = f - 64;  hl = r & 1; r >>= 1; s = r & 3; tau = r >> 2; }
    else              { cell = 3; int r = f - 192; hl = r & 1; s = r >> 1; tau = 0; }
    int g = tau >> 2, U = tau & 3, u = U * 16 + n;
    float sc = (cell == 3) ? 1.0f : ((g == 2) ? 2.0f * L2E : L2E);
    unsigned int dw[4];
    for (int d = 0; d < 4; d++) {
        unsigned int packed = 0;
        for (int e = 0; e < 2; e++) {
            int jj = d * 2 + e;
            int k = s * 32 + qq * 8 + jj;
            float val = 0.f;
            if (cell == 1) {
                if (u < HH) {
                    if (k < HH)       val = Whh1[(g * HH + u) * HH + k];
                    else if (k == 51) val = bih1[g * HH + u] + bhh1[g * HH + u];
                    else              val = Wih1[g * HH + u];   // k=52,53
                }
            } else if (cell == 2) {
                if (u < HH) {
                    if (k < 64) {
                        if (k < HH)       val = Wih2[(g * HH + u) * HH + k];
                        else if (k == 51) val = bih2[g * HH + u] + bhh2[g * HH + u];
                        // k=52,53 stay 0 (x pass-through)
                    } else {
                        int k2 = k - 64;
                        if (k2 < HH) val = Whh2[(g * HH + u) * HH + k2];
                    }
                }
            } else {
                if (n == 0) {
                    if (k < HH)       val = Wlin[k];
                    else if (k == 51) val = blin[0];
                }
            }
            val *= sc;
            _Float16 hi = (_Float16)val;
            unsigned short bits;
            if (hl) { float lo = val - (float)hi; bits = f2h_bits(lo); }
            else    { bits = __builtin_bit_cast(unsigned short, hi); }
            packed |= ((unsigned int)bits) << (16 * e);
        }
        dw[d] = packed;
    }
    frags[f * 64 + lane] = make_uint4(dw[0], dw[1], dw[2], dw[3]);
}

// -------------------------------------------------------------------------
// R9 base (256.2us: single-fp16 weights + fused-rcp tail + lgkm barrier)
// + PACKED-f32 tail ONLY (the exonerated half of R8):
// R8's counters showed VALU-busy fell 109.7->103.1 us-equiv from packing
// while the bundled d+=p MFMA-tree caused the regression (accvgpr->VALU
// hazard NOPs on the critical path). This round isolates the packing:
// FTAIL on float2 vectors -> v_pk_{mul,add,fma}_f32. Per-element op
// sequence is IDENTICAL (5 exp2 + 2 rcp, same FMA order) -> bit-identical
// absmax. MFMA schedule untouched from R9 (4 interleaved 4-deep chains).
// -------------------------------------------------------------------------
__launch_bounds__(512, 2)
__global__ void lstm_main(const float* __restrict__ input,
                          const uint4* __restrict__ frags,
                          float* __restrict__ out) {
    __shared__ __align__(16) unsigned int h1[2][16][36];
    __shared__ __align__(16) unsigned int h2[2][16][36];
    __shared__ __align__(16) float xb[(TT + 1) * 16];    // [t][b], row TT = 0

    const int tid  = threadIdx.x;
    const int lane = tid & 63;
    const int w    = tid >> 6;
    const int l15  = lane & 15;
    const int q    = lane >> 4;
    const int b0g  = blockIdx.x * NB;
    const bool c2w = (w < 4);
    const int U    = c2w ? w : (w - 4);
    const int uc   = U * 16 + l15;
    const bool uok = (uc < HH);

    for (int i = tid; i < 2 * 16 * 36; i += 512) {
        ((unsigned*)h1)[i] = 0; ((unsigned*)h2)[i] = 0;
    }
    for (int c = 0; c < 2; c++) {
        int flat = tid + c * 512;
        int b = flat >> 6, t0 = (flat & 63) * 4;
        float4 v = *(const float4*)&input[(size_t)(b0g + b) * TT + t0];
        xb[(t0 + 0) * 16 + b] = v.x; xb[(t0 + 1) * 16 + b] = v.y;
        xb[(t0 + 2) * 16 + b] = v.z; xb[(t0 + 3) * 16 + b] = v.w;
    }
    if (tid < 16) xb[TT * 16 + tid] = 0.f;
    __syncthreads();
    if (tid < 16) {                         // initial hooks in h1 parity 1
        int b = tid;
        int wi51 = ((25 + 4 * (b >> 1)) & 31) * 2 + 1;   // u=51 (bias col)
        int wi52 = ((26 + 4 * (b >> 1)) & 31) * 2 + 0;   // u=52 (x_hi)
        int wi53 = ((26 + 4 * (b >> 1)) & 31) * 2 + 1;   // u=53 (x_lo)
        ((unsigned short*)&h1[1][b][0])[wi51] = 0x3C00;  // fp16(1.0)
        float x0 = input[(size_t)(b0g + b) * TT];
        _Float16 xh = (_Float16)x0;
        ((unsigned short*)&h1[1][b][0])[wi52] = __builtin_bit_cast(unsigned short, xh);
        ((unsigned short*)&h1[1][b][0])[wi53] = f2h_bits(x0 - (float)xh);
    }

    // weight-stationary fragments -- HI ONLY
    half8 fr[16];
    if (c2w) {
#pragma unroll
        for (int g = 0; g < 4; g++) {
            int tau = g * 4 + U;
#pragma unroll
            for (int s = 0; s < 4; s++)
                fr[g * 4 + s] = __builtin_bit_cast(half8, frags[(64 + (tau * 4 + s) * 2) * 64 + lane]);
        }
    } else {
#pragma unroll
        for (int g = 0; g < 4; g++) {
            int tau = g * 4 + U;
#pragma unroll
            for (int s = 0; s < 2; s++)
                fr[g * 2 + s] = __builtin_bit_cast(half8, frags[((tau * 2 + s) * 2) * 64 + lane]);
        }
#pragma unroll
        for (int s = 0; s < 2; s++)         // head frags on ALL c1 waves
            fr[8 + s] = __builtin_bit_cast(half8, frags[(192 + s * 2) * 64 + lane]);
    }
    floatx4 zacc = {0.f, 0.f, 0.f, 0.f};
    float2v cst2[2] = {{0.f, 0.f}, {0.f, 0.f}};
    const int baseA = (q * 4 + 4 * (l15 >> 1)) & 31;
    const int baseB = (baseA + 16) & 31;

    __syncthreads();

// fused activation tail on float2 pairs (r01, r23). Per-element math is
// EXACTLY R9's FTAIL: 5 exp2 + 2 rcp; v_pk_* for the rest.
#define FTAIL_PK(D0, D1, D2, D3, HVA)                                           \
    _Pragma("unroll")                                                           \
    for (int p = 0; p < 2; p++) {                                               \
        const float2v one = {1.f, 1.f};                                         \
        float2v ei, ef, eg, eo;                                                 \
        ei.x = exp2_fast(-(D0)[2*p]); ei.y = exp2_fast(-(D0)[2*p+1]);           \
        ef.x = exp2_fast(-(D1)[2*p]); ef.y = exp2_fast(-(D1)[2*p+1]);           \
        eg.x = exp2_fast( (D2)[2*p]); eg.y = exp2_fast( (D2)[2*p+1]);           \
        eo.x = exp2_fast(-(D3)[2*p]); eo.y = exp2_fast(-(D3)[2*p+1]);           \
        float2v Fv = one + ef;                                                  \
        float2v Pv = (one + ei) * (one + eg);                                   \
        float2v FP = Fv * Pv;                                                   \
        float2v Rv; Rv.x = rcp_fast(FP.x); Rv.y = rcp_fast(FP.y);               \
        float2v f1v = Rv * Pv;                                                  \
        float2v tv  = fma2((float2v){2.f*L2E, 2.f*L2E}, eg,                     \
                           (float2v){-2.f*L2E, -2.f*L2E});                      \
        float2v igt = tv * (Rv * Fv);                                           \
        float2v cn  = fma2(f1v, cst2[p], igt);                                  \
        cst2[p] = cn;                                                           \
        float2v ec; ec.x = exp2_fast(cn.x); ec.y = exp2_fast(cn.y);             \
        float2v Ov = one + eo;                                                  \
        float2v SA = fma2(Ov, ec, Ov);                                          \
        float2v Sv; Sv.x = rcp_fast(SA.x); Sv.y = rcp_fast(SA.y);               \
        float2v hv2 = (ec - one) * Sv;                                          \
        (HVA)[2*p] = hv2.x; (HVA)[2*p+1] = hv2.y;                               \
    }

#define STEP(IT, P)                                                             \
    do {                                                                        \
        if (c2w) {                                                              \
            if ((IT) >= 1 && (IT) <= TT) {       /* cell2 -> h2(IT-1) */        \
                half8 a0 = *(const half8*)&h1[1 - (P)][l15][baseA];             \
                half8 a1 = *(const half8*)&h1[1 - (P)][l15][baseB];             \
                half8 a2 = *(const half8*)&h2[(P)][l15][baseA];                 \
                half8 a3 = *(const half8*)&h2[(P)][l15][baseB];                 \
                floatx4 d0, d1, d2, d3;                                         \
                d0 = MFMA16F(a0, fr[0],  zacc);                                 \
                d1 = MFMA16F(a0, fr[4],  zacc);                                 \
                d2 = MFMA16F(a0, fr[8],  zacc);                                 \
                d3 = MFMA16F(a0, fr[12], zacc);                                 \
                d0 = MFMA16F(a1, fr[1],  d0);                                   \
                d1 = MFMA16F(a1, fr[5],  d1);                                   \
                d2 = MFMA16F(a1, fr[9],  d2);                                   \
                d3 = MFMA16F(a1, fr[13], d3);                                   \
                d0 = MFMA16F(a2, fr[2],  d0);                                   \
                d1 = MFMA16F(a2, fr[6],  d1);                                   \
                d2 = MFMA16F(a2, fr[10], d2);                                   \
                d3 = MFMA16F(a2, fr[14], d3);                                   \
                d0 = MFMA16F(a3, fr[3],  d0);                                   \
                d1 = MFMA16F(a3, fr[7],  d1);                                   \
                d2 = MFMA16F(a3, fr[11], d2);                                   \
                d3 = MFMA16F(a3, fr[15], d3);                                   \
                float hv_s[4];                                                  \
                FTAIL_PK(d0, d1, d2, d3, hv_s)                                  \
                _Pragma("unroll")                                               \
                for (int r = 0; r < 4; r++) {                                   \
                    float hv = uok ? hv_s[r] : (uc == 51 ? 1.0f : 0.f);         \
                    int bb = q * 4 + r;                                         \
                    int wi = (((uc >> 1) + 4 * (bb >> 1)) & 31) * 2 + (uc & 1); \
                    ((unsigned short*)&h2[1 - (P)][bb][0])[wi] = f2h_bits(hv);  \
                }                                                               \
            }                                                                   \
        } else {                                                                \
            if ((IT) <= TT - 1) {                /* cell1 -> h1(IT) */          \
                float4 xn = {0.f, 0.f, 0.f, 0.f};                               \
                if (uc >= HH) xn = *(const float4*)&xb[((IT) + 1) * 16 + q * 4]; \
                half8 a0 = *(const half8*)&h1[1 - (P)][l15][baseA];             \
                half8 a1 = *(const half8*)&h1[1 - (P)][l15][baseB];             \
                floatx4 d0, d1, d2, d3;                                         \
                d0 = MFMA16F(a0, fr[0], zacc);                                  \
                d1 = MFMA16F(a0, fr[2], zacc);                                  \
                d2 = MFMA16F(a0, fr[4], zacc);                                  \
                d3 = MFMA16F(a0, fr[6], zacc);                                  \
                d0 = MFMA16F(a1, fr[1], d0);                                    \
                d1 = MFMA16F(a1, fr[3], d1);                                    \
                d2 = MFMA16F(a1, fr[5], d2);                                    \
                d3 = MFMA16F(a1, fr[7], d3);                                    \
                float hv_s[4];                                                  \
                FTAIL_PK(d0, d1, d2, d3, hv_s)                                  \
                _Pragma("unroll")                                               \
                for (int r = 0; r < 4; r++) {                                   \
                    float hv = uok ? hv_s[r]                                    \
                             : (uc == 51 ? 1.0f                                 \
                             : (uc == 52 ? xn[r]                                \
                             : (uc == 53 ? xn[r] - (float)(_Float16)xn[r] : 0.f))); \
                    int bb = q * 4 + r;                                         \
                    int wi = (((uc >> 1) + 4 * (bb >> 1)) & 31) * 2 + (uc & 1); \
                    ((unsigned short*)&h1[(P)][bb][0])[wi] = f2h_bits(hv);      \
                }                                                               \
            }                                                                   \
            if ((IT) >= 2 && (w - 4) == ((IT) & 3)) {   /* rotated head */      \
                half8 a2 = *(const half8*)&h2[(P)][l15][baseA];                 \
                half8 a3 = *(const half8*)&h2[(P)][l15][baseB];                 \
                floatx4 ho;                                                     \
                ho = MFMA16F(a2, fr[8], zacc);                                  \
                ho = MFMA16F(a3, fr[9], ho);                                    \
                if (l15 == 0) {                                                 \
                    _Pragma("unroll")                                           \
                    for (int r = 0; r < 4; r++)                                 \
                        out[(size_t)(b0g + q * 4 + r) * TT + ((IT) - 2)] = ho[r]; \
                }                                                               \
            }                                                                   \
        }                                                                       \
        bar_lgkm();                                                             \
    } while (0)

    for (int itp = 0; itp < TT + 2; itp += 2) {
        STEP(itp, 0);
        STEP(itp + 1, 1);
    }
#undef STEP
#undef FTAIL_PK
}

extern "C" void kernel_launch(void* const* d_in, const int* in_sizes, int n_in,
                              void* d_out, int out_size, void* d_ws, size_t ws_size,
                              hipStream_t stream) {
    const float* input = (const float*)d_in[0];
    const float* Wih1  = (const float*)d_in[1];
    const float* Whh1  = (const float*)d_in[2];
    const float* bih1  = (const float*)d_in[3];
    const float* bhh1  = (const float*)d_in[4];
    const float* Wih2  = (const float*)d_in[5];
    const float* Whh2  = (const float*)d_in[6];
    const float* bih2  = (const float*)d_in[7];
    const float* bhh2  = (const float*)d_in[8];
    const float* Wlin  = (const float*)d_in[9];
    const float* blin  = (const float*)d_in[10];

    uint4* frags = (uint4*)d_ws;            // 196 frags * 1 KiB
    int B = in_sizes[0] / TT;               // 4096

    lstm_prep<<<49, 256, 0, stream>>>(Whh1, Wih1, bih1, bhh1, Wih2, Whh2,
                                      bih2, bhh2, Wlin, blin, frags);
    lstm_main<<<B / NB, 512, 0, stream>>>(input, frags, (float*)d_out);
}

// Round 11
// 305.368 us; speedup vs baseline: 1.0382x; 1.0382x over previous
//
#include <hip/hip_runtime.h>

#define HH 51
#define TT 256
#define NB 16
#define L2E 1.442695041f

typedef __attribute__((ext_vector_type(8))) _Float16 half8;
typedef __attribute__((ext_vector_type(4))) float   floatx4;

#define MFMA16F(A,B,C) __builtin_amdgcn_mfma_f32_16x16x32_f16((A),(B),(C),0,0,0)

__device__ __forceinline__ float rcp_fast(float x) { return __builtin_amdgcn_rcpf(x); }
#if __has_builtin(__builtin_amdgcn_exp2f)
__device__ __forceinline__ float exp2_fast(float x) { return __builtin_amdgcn_exp2f(x); }
#else
__device__ __forceinline__ float exp2_fast(float x) { return __expf(0.69314718056f * x); }
#endif
__device__ __forceinline__ unsigned short f2h_bits(float v) {
    return __builtin_bit_cast(unsigned short, (_Float16)v);
}

// barrier that drains ONLY lgkmcnt (R9 base)
__device__ __forceinline__ void bar_lgkm() {
    asm volatile("s_waitcnt lgkmcnt(0)" ::: "memory");
    __builtin_amdgcn_s_barrier();
    asm volatile("" ::: "memory");
}

// ------------- weight pre-pack: fp16 hi/lo fragments, K-column folding ---
// (UNCHANGED. Main kernel loads ONLY the hi fragments (hl=0).)
__global__ void lstm_prep(const float* __restrict__ Whh1, const float* __restrict__ Wih1,
                          const float* __restrict__ bih1, const float* __restrict__ bhh1,
                          const float* __restrict__ Wih2, const float* __restrict__ Whh2,
                          const float* __restrict__ bih2, const float* __restrict__ bhh2,
                          const float* __restrict__ Wlin, const float* __restrict__ blin,
                          uint4* __restrict__ frags) {
    int tid = blockIdx.x * blockDim.x + threadIdx.x;
    if (tid >= 196 * 64) return;
    int f = tid >> 6, lane = tid & 63;
    int n = lane & 15, qq = lane >> 4;
    int hl, s, tau, cell;
    if (f < 64)       { cell = 1; int r = f;       hl = r & 1; r >>= 1; s = r & 1; tau = r >> 1; }
    else if (f < 192) { cell = 2; int r = f - 64;  hl = r & 1; r >>= 1; s = r & 3; tau = r >> 2; }
    else              { cell = 3; int r = f - 192; hl = r & 1; s = r >> 1; tau = 0; }
    int g = tau >> 2, U = tau & 3, u = U * 16 + n;
    float sc = (cell == 3) ? 1.0f : ((g == 2) ? 2.0f * L2E : L2E);
    unsigned int dw[4];
    for (int d = 0; d < 4; d++) {
        unsigned int packed = 0;
        for (int e = 0; e < 2; e++) {
            int jj = d * 2 + e;
            int k = s * 32 + qq * 8 + jj;
            float val = 0.f;
            if (cell == 1) {
                if (u < HH) {
                    if (k < HH)       val = Whh1[(g * HH + u) * HH + k];
                    else if (k == 51) val = bih1[g * HH + u] + bhh1[g * HH + u];
                    else              val = Wih1[g * HH + u];   // k=52,53
                }
            } else if (cell == 2) {
                if (u < HH) {
                    if (k < 64) {
                        if (k < HH)       val = Wih2[(g * HH + u) * HH + k];
                        else if (k == 51) val = bih2[g * HH + u] + bhh2[g * HH + u];
                        // k=52,53 stay 0 (x pass-through)
                    } else {
                        int k2 = k - 64;
                        if (k2 < HH) val = Whh2[(g * HH + u) * HH + k2];
                    }
                }
            } else {
                if (n == 0) {
                    if (k < HH)       val = Wlin[k];
                    else if (k == 51) val = blin[0];
                }
            }
            val *= sc;
            _Float16 hi = (_Float16)val;
            unsigned short bits;
            if (hl) { float lo = val - (float)hi; bits = f2h_bits(lo); }
            else    { bits = __builtin_bit_cast(unsigned short, hi); }
            packed |= ((unsigned int)bits) << (16 * e);
        }
        dw[d] = packed;
    }
    frags[f * 64 + lane] = make_uint4(dw[0], dw[1], dw[2], dw[3]);
}

// -------------------------------------------------------------------------
// R9 revert (verified best, 256.2us: single-fp16 weights + fused-rcp scalar
// tail + lgkm-only barrier) + loop micro-opts:
//  - R10 post-mortem: float2-packed tail REGRESSED (coupled the 4
//    independent tail chains into 2, exposing trans latency) -> scalar
//    FTAIL restored verbatim.
//  - 4-step unroll: (IT&3) becomes compile-time -> head-rotation predicate
//    is a constant compare per unrolled position; loop overhead halved.
//  - h-write uint indices wi[r] hoisted (loop-invariant).
// Numerics byte-identical to R9 -> absmax bit-identical 2.441e-4.
// -------------------------------------------------------------------------
__launch_bounds__(512, 2)
__global__ void lstm_main(const float* __restrict__ input,
                          const uint4* __restrict__ frags,
                          float* __restrict__ out) {
    __shared__ __align__(16) unsigned int h1[2][16][36];
    __shared__ __align__(16) unsigned int h2[2][16][36];
    __shared__ __align__(16) float xb[(TT + 1) * 16];    // [t][b], row TT = 0

    const int tid  = threadIdx.x;
    const int lane = tid & 63;
    const int w    = tid >> 6;
    const int l15  = lane & 15;
    const int q    = lane >> 4;
    const int b0g  = blockIdx.x * NB;
    const bool c2w = (w < 4);
    const int U    = c2w ? w : (w - 4);
    const int uc   = U * 16 + l15;
    const bool uok = (uc < HH);

    for (int i = tid; i < 2 * 16 * 36; i += 512) {
        ((unsigned*)h1)[i] = 0; ((unsigned*)h2)[i] = 0;
    }
    for (int c = 0; c < 2; c++) {
        int flat = tid + c * 512;
        int b = flat >> 6, t0 = (flat & 63) * 4;
        float4 v = *(const float4*)&input[(size_t)(b0g + b) * TT + t0];
        xb[(t0 + 0) * 16 + b] = v.x; xb[(t0 + 1) * 16 + b] = v.y;
        xb[(t0 + 2) * 16 + b] = v.z; xb[(t0 + 3) * 16 + b] = v.w;
    }
    if (tid < 16) xb[TT * 16 + tid] = 0.f;
    __syncthreads();
    if (tid < 16) {                         // initial hooks in h1 parity 1
        int b = tid;
        int wi51 = ((25 + 4 * (b >> 1)) & 31) * 2 + 1;   // u=51 (bias col)
        int wi52 = ((26 + 4 * (b >> 1)) & 31) * 2 + 0;   // u=52 (x_hi)
        int wi53 = ((26 + 4 * (b >> 1)) & 31) * 2 + 1;   // u=53 (x_lo)
        ((unsigned short*)&h1[1][b][0])[wi51] = 0x3C00;  // fp16(1.0)
        float x0 = input[(size_t)(b0g + b) * TT];
        _Float16 xh = (_Float16)x0;
        ((unsigned short*)&h1[1][b][0])[wi52] = __builtin_bit_cast(unsigned short, xh);
        ((unsigned short*)&h1[1][b][0])[wi53] = f2h_bits(x0 - (float)xh);
    }

    // weight-stationary fragments -- HI ONLY
    half8 fr[16];
    if (c2w) {
#pragma unroll
        for (int g = 0; g < 4; g++) {
            int tau = g * 4 + U;
#pragma unroll
            for (int s = 0; s < 4; s++)
                fr[g * 4 + s] = __builtin_bit_cast(half8, frags[(64 + (tau * 4 + s) * 2) * 64 + lane]);
        }
    } else {
#pragma unroll
        for (int g = 0; g < 4; g++) {
            int tau = g * 4 + U;
#pragma unroll
            for (int s = 0; s < 2; s++)
                fr[g * 2 + s] = __builtin_bit_cast(half8, frags[((tau * 2 + s) * 2) * 64 + lane]);
        }
#pragma unroll
        for (int s = 0; s < 2; s++)         // head frags on ALL c1 waves
            fr[8 + s] = __builtin_bit_cast(half8, frags[(192 + s * 2) * 64 + lane]);
    }
    floatx4 zacc = {0.f, 0.f, 0.f, 0.f};
    float cst[4] = {0.f, 0.f, 0.f, 0.f};
    const int baseA = (q * 4 + 4 * (l15 >> 1)) & 31;
    const int baseB = (baseA + 16) & 31;

    // hoisted h-write half-indices (loop-invariant): row bb = q*4+r
    int wiv[4];
#pragma unroll
    for (int r = 0; r < 4; r++) {
        int bb = q * 4 + r;
        wiv[r] = (((uc >> 1) + 4 * (bb >> 1)) & 31) * 2 + (uc & 1);
    }

    __syncthreads();

// fused activation tail: 5 exp2 + 2 rcp per element (R9 scalar, verified)
#define FTAIL(D0, D1, D2, D3, HVA)                                              \
    _Pragma("unroll")                                                           \
    for (int r = 0; r < 4; r++) {                                               \
        float ei = exp2_fast(-(D0)[r]);                                         \
        float ef = exp2_fast(-(D1)[r]);                                         \
        float eg = exp2_fast( (D2)[r]);                                         \
        float eo = exp2_fast(-(D3)[r]);                                         \
        float Fv = 1.f + ef;                                                    \
        float Pv = (1.f + ei) * (1.f + eg);                                     \
        float Rv = rcp_fast(Fv * Pv);                                           \
        float f1v = Rv * Pv;                                                    \
        float tv  = fmaf(2.f * L2E, eg, -2.f * L2E);                            \
        float igt = tv * (Rv * Fv);                                             \
        float cn  = fmaf(f1v, cst[r], igt);                                     \
        cst[r] = cn;                                                            \
        float ec = exp2_fast(cn);                                               \
        float Ov = 1.f + eo;                                                    \
        float Sv = rcp_fast(fmaf(Ov, ec, Ov));                                  \
        (HVA)[r] = (ec - 1.f) * Sv;                                             \
    }

// KP = compile-time (IT & 3) so the head predicate is a constant compare.
#define STEP(IT, P, KP)                                                         \
    do {                                                                        \
        if (c2w) {                                                              \
            if ((IT) >= 1 && (IT) <= TT) {       /* cell2 -> h2(IT-1) */        \
                half8 a0 = *(const half8*)&h1[1 - (P)][l15][baseA];             \
                half8 a1 = *(const half8*)&h1[1 - (P)][l15][baseB];             \
                half8 a2 = *(const half8*)&h2[(P)][l15][baseA];                 \
                half8 a3 = *(const half8*)&h2[(P)][l15][baseB];                 \
                floatx4 d0, d1, d2, d3;                                         \
                d0 = MFMA16F(a0, fr[0],  zacc);                                 \
                d1 = MFMA16F(a0, fr[4],  zacc);                                 \
                d2 = MFMA16F(a0, fr[8],  zacc);                                 \
                d3 = MFMA16F(a0, fr[12], zacc);                                 \
                d0 = MFMA16F(a1, fr[1],  d0);                                   \
                d1 = MFMA16F(a1, fr[5],  d1);                                   \
                d2 = MFMA16F(a1, fr[9],  d2);                                   \
                d3 = MFMA16F(a1, fr[13], d3);                                   \
                d0 = MFMA16F(a2, fr[2],  d0);                                   \
                d1 = MFMA16F(a2, fr[6],  d1);                                   \
                d2 = MFMA16F(a2, fr[10], d2);                                   \
                d3 = MFMA16F(a2, fr[14], d3);                                   \
                d0 = MFMA16F(a3, fr[3],  d0);                                   \
                d1 = MFMA16F(a3, fr[7],  d1);                                   \
                d2 = MFMA16F(a3, fr[11], d2);                                   \
                d3 = MFMA16F(a3, fr[15], d3);                                   \
                float hv_s[4];                                                  \
                FTAIL(d0, d1, d2, d3, hv_s)                                     \
                _Pragma("unroll")                                               \
                for (int r = 0; r < 4; r++) {                                   \
                    float hv = uok ? hv_s[r] : (uc == 51 ? 1.0f : 0.f);         \
                    ((unsigned short*)&h2[1 - (P)][q * 4 + r][0])[wiv[r]] = f2h_bits(hv); \
                }                                                               \
            }                                                                   \
        } else {                                                                \
            if ((IT) <= TT - 1) {                /* cell1 -> h1(IT) */          \
                float4 xn = {0.f, 0.f, 0.f, 0.f};                               \
                if (uc >= HH) xn = *(const float4*)&xb[((IT) + 1) * 16 + q * 4]; \
                half8 a0 = *(const half8*)&h1[1 - (P)][l15][baseA];             \
                half8 a1 = *(const half8*)&h1[1 - (P)][l15][baseB];             \
                floatx4 d0, d1, d2, d3;                                         \
                d0 = MFMA16F(a0, fr[0], zacc);                                  \
                d1 = MFMA16F(a0, fr[2], zacc);                                  \
                d2 = MFMA16F(a0, fr[4], zacc);                                  \
                d3 = MFMA16F(a0, fr[6], zacc);                                  \
                d0 = MFMA16F(a1, fr[1], d0);                                    \
                d1 = MFMA16F(a1, fr[3], d1);                                    \
                d2 = MFMA16F(a1, fr[5], d2);                                    \
                d3 = MFMA16F(a1, fr[7], d3);                                    \
                float hv_s[4];                                                  \
                FTAIL(d0, d1, d2, d3, hv_s)                                     \
                _Pragma("unroll")                                               \
                for (int r = 0; r < 4; r++) {                                   \
                    float hv = uok ? hv_s[r]                                    \
                             : (uc == 51 ? 1.0f                                 \
                             : (uc == 52 ? xn[r]                                \
                             : (uc == 53 ? xn[r] - (float)(_Float16)xn[r] : 0.f))); \
                    ((unsigned short*)&h1[(P)][q * 4 + r][0])[wiv[r]] = f2h_bits(hv); \
                }                                                               \
            }                                                                   \
            if ((IT) >= 2 && (w - 4) == (KP)) {         /* rotated head */      \
                half8 a2 = *(const half8*)&h2[(P)][l15][baseA];                 \
                half8 a3 = *(const half8*)&h2[(P)][l15][baseB];                 \
                floatx4 ho;                                                     \
                ho = MFMA16F(a2, fr[8], zacc);                                  \
                ho = MFMA16F(a3, fr[9], ho);                                    \
                if (l15 == 0) {                                                 \
                    _Pragma("unroll")                                           \
                    for (int r = 0; r < 4; r++)                                 \
                        out[(size_t)(b0g + q * 4 + r) * TT + ((IT) - 2)] = ho[r]; \
                }                                                               \
            }                                                                   \
        }                                                                       \
        bar_lgkm();                                                             \
    } while (0)

    // 258 steps = 64 x 4-step unrolled iterations + 2 tail steps.
    // itp is a multiple of 4 inside the loop -> (itp+k)&3 == k (compile-time).
#pragma unroll 1
    for (int itp = 0; itp < TT; itp += 4) {
        STEP(itp,     0, 0);
        STEP(itp + 1, 1, 1);
        STEP(itp + 2, 0, 2);
        STEP(itp + 3, 1, 3);
    }
    STEP(TT,     0, 0);   // IT = 256 (TT & 3 == 0)
    STEP(TT + 1, 1, 1);   // IT = 257
#undef STEP
#undef FTAIL
}

extern "C" void kernel_launch(void* const* d_in, const int* in_sizes, int n_in,
                              void* d_out, int out_size, void* d_ws, size_t ws_size,
                              hipStream_t stream) {
    const float* input = (const float*)d_in[0];
    const float* Wih1  = (const float*)d_in[1];
    const float* Whh1  = (const float*)d_in[2];
    const float* bih1  = (const float*)d_in[3];
    const float* bhh1  = (const float*)d_in[4];
    const float* Wih2  = (const float*)d_in[5];
    const float* Whh2  = (const float*)d_in[6];
    const float* bih2  = (const float*)d_in[7];
    const float* bhh2  = (const float*)d_in[8];
    const float* Wlin  = (const float*)d_in[9];
    const float* blin  = (const float*)d_in[10];

    uint4* frags = (uint4*)d_ws;            // 196 frags * 1 KiB
    int B = in_sizes[0] / TT;               // 4096

    lstm_prep<<<49, 256, 0, stream>>>(Whh1, Wih1, bih1, bhh1, Wih2, Whh2,
                                      bih2, bhh2, Wlin, blin, frags);
    lstm_main<<<B / NB, 512, 0, stream>>>(input, frags, (float*)d_out);
}